// Round 5
// baseline (171928.442 us; speedup 1.0000x reference)
//
#include <hip/hip_runtime.h>
#include <stdint.h>

// ---------------------------------------------------------------------------
// Seq2seq LSTM autoencoder (T=4096, H=1024, L=2), fp32 end-to-end.
// Round 5: lockstep two-layer scans, spill-free.
//   kernel1: enc L0+L1 lockstep   kernel2: dec L0+L1 lockstep + fused proj
// Heterogeneous grid of 384 blocks x 512 threads (<=512 residency slots at
// 2 blocks/CU; __launch_bounds__(512,4) caps regs at 128/thread):
//   blocks 0..127  = L0 role: 8 h-rows, W_hh resident (64 fl/thr, K=1024).
//     enc: W_ih0 @ x[i+1] computed one step AHEAD with W_ih0 STREAMED from
//     L2 (no residency cost, off critical path). dec: input gates constant.
//   blocks 128..383 = L1 role: 4 h-rows, W_ih+W_hh resident (64 fl/thr,
//     K=2048 over concat[h0 | h1]). dec: projection fused (8 oW fl/thr),
//     out row written by tail; no separate proj kernel.
// Slot i of the stream holds h0[i-1] (entries 0..1023) and h1[i-2]
// (1024..2047) as fp32 split into two tagged dwords (MAGIC<<16)|half.
// L1 inputs are always stored one iteration earlier -> only the L0 self-
// recurrence is latency-critical. Enc/dec reuse the region with M1/M2.
// ---------------------------------------------------------------------------

#define T_STEPS 4096
#define H_DIM   1024
#define SLOT_DW 4096
#define NSLOT   4098
#define LSTRIDE ((size_t)4096*1024)
#define M1 0x7E57u
#define M2 0x7E58u
#define PANIC_ITERS (1u<<27)

using u32 = uint32_t;
using f4 = float4;

static __device__ __forceinline__ float sigf(float x){ return 1.0f/(1.0f+__expf(-x)); }
static __device__ __forceinline__ float tanh_f(float x){
  x = fminf(20.f, fmaxf(-20.f, x));
  float e = __expf(-2.f*x);
  return (1.f-e)/(1.f+e);
}

static __device__ __forceinline__ void store_h(u32* slot, u32 magic, int e, float h){
  u32 b=__float_as_uint(h);
  __hip_atomic_store(slot+2*e,   (magic<<16)|(b&0xFFFFu), __ATOMIC_RELAXED,__HIP_MEMORY_SCOPE_AGENT);
  __hip_atomic_store(slot+2*e+1, (magic<<16)|(b>>16),     __ATOMIC_RELAXED,__HIP_MEMORY_SCOPE_AGENT);
}

// poll 4 tagged dwords -> 2 fp32 into LDS (float2)
static __device__ __forceinline__ void poll_fill4(const u32* q, u32 magic,
                                                  float* dst, u32* panic){
  u32 v[4]; u32 it=0;
  for(;;){
    #pragma unroll
    for(int m=0;m<4;m++) v[m]=__hip_atomic_load(q+m,__ATOMIC_RELAXED,__HIP_MEMORY_SCOPE_AGENT);
    bool ok=true;
    #pragma unroll
    for(int m=0;m<4;m++) ok = ok && ((v[m]>>16)==magic);
    if(ok) break;
    ++it;
    if((it&511u)==0u){
      if(__hip_atomic_load(panic,__ATOMIC_RELAXED,__HIP_MEMORY_SCOPE_AGENT)==0xDEADBEEFu) break;
      if(it>PANIC_ITERS){ __hip_atomic_store(panic,0xDEADBEEFu,__ATOMIC_RELAXED,__HIP_MEMORY_SCOPE_AGENT); break; }
    }
    __builtin_amdgcn_s_sleep(1);
  }
  float2 f;
  f.x=__uint_as_float((v[0]&0xFFFFu)|(v[1]<<16));
  f.y=__uint_as_float((v[2]&0xFFFFu)|(v[3]<<16));
  *(float2*)dst=f;
}

// poll 8 tagged dwords -> 4 fp32 into LDS (float4)
static __device__ __forceinline__ void poll_fill8(const u32* q, u32 magic,
                                                  float* dst, u32* panic){
  u32 v[8]; u32 it=0;
  for(;;){
    #pragma unroll
    for(int m=0;m<8;m++) v[m]=__hip_atomic_load(q+m,__ATOMIC_RELAXED,__HIP_MEMORY_SCOPE_AGENT);
    bool ok=true;
    #pragma unroll
    for(int m=0;m<8;m++) ok = ok && ((v[m]>>16)==magic);
    if(ok) break;
    ++it;
    if((it&511u)==0u){
      if(__hip_atomic_load(panic,__ATOMIC_RELAXED,__HIP_MEMORY_SCOPE_AGENT)==0xDEADBEEFu) break;
      if(it>PANIC_ITERS){ __hip_atomic_store(panic,0xDEADBEEFu,__ATOMIC_RELAXED,__HIP_MEMORY_SCOPE_AGENT); break; }
    }
    __builtin_amdgcn_s_sleep(1);
  }
  f4 f;
  f.x=__uint_as_float((v[0]&0xFFFFu)|(v[1]<<16));
  f.y=__uint_as_float((v[2]&0xFFFFu)|(v[3]<<16));
  f.z=__uint_as_float((v[4]&0xFFFFu)|(v[5]<<16));
  f.w=__uint_as_float((v[6]&0xFFFFu)|(v[7]<<16));
  *(f4*)dst=f;
}

#define RED4(A,B,C,D) do{ _Pragma("unroll") \
  for(int o_=32;o_;o_>>=1){ A+=__shfl_down(A,o_,64); B+=__shfl_down(B,o_,64); \
                            C+=__shfl_down(C,o_,64); D+=__shfl_down(D,o_,64);} }while(0)

// streamed x-gate dot for step I (enc L0): W_ih0 from L2, x from global
#define XDOT(I,PAR) do{ \
  const float* xp_ = x + (size_t)(I)*H_DIM + l*16; \
  const float* wp_ = Wih + (size_t)grow0*H_DIM + l*16; \
  f4 xv_[4]; \
  xv_[0]=*(const f4*)(xp_);   xv_[1]=*(const f4*)(xp_+4); \
  xv_[2]=*(const f4*)(xp_+8); xv_[3]=*(const f4*)(xp_+12); \
  float xa_[4]={0.f,0.f,0.f,0.f}; \
  _Pragma("unroll") \
  for(int r_=0;r_<4;r_++){ \
    _Pragma("unroll") \
    for(int kq_=0;kq_<4;kq_++){ \
      f4 w_=*(const f4*)(wp_+(size_t)r_*H_DIM+kq_*4); \
      xa_[r_]+=xv_[kq_].x*w_.x+xv_[kq_].y*w_.y+xv_[kq_].z*w_.z+xv_[kq_].w*w_.w; \
    } \
  } \
  RED4(xa_[0],xa_[1],xa_[2],xa_[3]); \
  if(l==0){ gl2[PAR][wv*4+0]=xa_[0]; gl2[PAR][wv*4+1]=xa_[1]; \
            gl2[PAR][wv*4+2]=xa_[2]; gl2[PAR][wv*4+3]=xa_[3]; } \
}while(0)

__global__ __launch_bounds__(512,4) void lstm_scan2(
    const float* __restrict__ x, const float* __restrict__ fh,
    u32* __restrict__ R, u32 magic,
    const float* __restrict__ Wih, const float* __restrict__ Whh,
    const float* __restrict__ bih, const float* __restrict__ bhh,
    float* __restrict__ F,           // [0..1023]c0fin [1024..2047]c1fin [2048..]h0fin
    float* __restrict__ fh_out,
    const float* __restrict__ oW, const float* __restrict__ ob,
    float* __restrict__ out, u32* __restrict__ panic, int isenc)
{
  // padded stage: element E at word E + 4*(E>>5); h0 part 0..1151, h1 1152..2303
  __shared__ __align__(16) float st[2304];
  __shared__ float gl[32];         // gate partials (+proj partials at 16..23)
  __shared__ float gl2[2][32];     // enc L0: x-gate pre-acts, parity buffered

  const int tid = threadIdx.x;
  const int wv = tid>>6, l = tid&63;

  if (blockIdx.x < 128) {
    // =========== L0 role: 8 h-rows, recurrent K=1024 ===========
    const int kb = blockIdx.x, hr0 = kb*8;
    const int g = wv&3, q = wv>>2;               // gate, row-quad
    const int grow0 = (g<<10) + hr0 + q*4;       // first of 4 gate rows
    const int sb = l*16 + ((l>>1)<<2);           // dot segment word base

    float wh[4][16];                              // W_hh rows, resident
    {
      const float* bp = Whh + (size_t)grow0*H_DIM + l*16;
      #pragma unroll
      for(int r=0;r<4;r++){
        #pragma unroll
        for(int kq=0;kq<4;kq++){
          f4 v=*(const f4*)(bp + (size_t)r*H_DIM + kq*4);
          wh[r][kq*4+0]=v.x; wh[r][kq*4+1]=v.y; wh[r][kq*4+2]=v.z; wh[r][kq*4+3]=v.w;
        }
      }
    }
    float bI=0,bF=0,bG=0,bO=0,c_st=0.f,h_st=0.f;
    float xq0=0,xq1=0,xq2=0,xq3=0;                // dec: constant input gates
    if(tid<8){
      int row=hr0+tid;
      bI=bih[row]+bhh[row];           bF=bih[row+1024]+bhh[row+1024];
      bG=bih[row+2048]+bhh[row+2048]; bO=bih[row+3072]+bhh[row+3072];
      if(!isenc){ c_st=F[row]; h_st=F[2048+row]; }
      store_h(R, magic, row, h_st);               // seed slot 0
    }
    if(!isenc){
      // one-shot constant gates: W_ih0 @ final_hidden (fp32, global weights)
      float2 fv = *(const float2*)(fh + tid*2);
      *(float2*)&st[tid*2 + ((tid>>4)<<2)] = fv;
      __syncthreads();
      float xa0=0,xa1=0,xa2=0,xa3=0;
      const float* wp = Wih + (size_t)grow0*H_DIM + l*16;
      #pragma unroll
      for(int kq=0;kq<4;kq++){
        f4 s=*(const f4*)&st[sb+kq*4];
        f4 w0=*(const f4*)(wp+kq*4);
        f4 w1=*(const f4*)(wp+H_DIM+kq*4);
        f4 w2=*(const f4*)(wp+2*H_DIM+kq*4);
        f4 w3=*(const f4*)(wp+3*H_DIM+kq*4);
        xa0+=s.x*w0.x+s.y*w0.y+s.z*w0.z+s.w*w0.w;
        xa1+=s.x*w1.x+s.y*w1.y+s.z*w1.z+s.w*w1.w;
        xa2+=s.x*w2.x+s.y*w2.y+s.z*w2.z+s.w*w2.w;
        xa3+=s.x*w3.x+s.y*w3.y+s.z*w3.z+s.w*w3.w;
      }
      RED4(xa0,xa1,xa2,xa3);
      if(l==0){ gl[wv*4+0]=xa0; gl[wv*4+1]=xa1; gl[wv*4+2]=xa2; gl[wv*4+3]=xa3; }
      __syncthreads();
      if(tid<8){
        int q2=tid>>2, r2=tid&3;
        xq0=gl[(((q2<<2)|0)<<2)+r2]; xq1=gl[(((q2<<2)|1)<<2)+r2];
        xq2=gl[(((q2<<2)|2)<<2)+r2]; xq3=gl[(((q2<<2)|3)<<2)+r2];
      }
      __syncthreads();
    } else {
      XDOT(0,0);                                  // prologue: x-gates for step 0
    }
    for(int i=0;i<T_STEPS;++i){
      poll_fill4(R + (size_t)i*SLOT_DW + tid*4, magic,
                 &st[tid*2 + ((tid>>4)<<2)], panic);
      __syncthreads();
      float a0=0,a1=0,a2=0,a3=0;
      #pragma unroll
      for(int kq=0;kq<4;kq++){
        f4 s=*(const f4*)&st[sb+kq*4];
        a0+=s.x*wh[0][kq*4]+s.y*wh[0][kq*4+1]+s.z*wh[0][kq*4+2]+s.w*wh[0][kq*4+3];
        a1+=s.x*wh[1][kq*4]+s.y*wh[1][kq*4+1]+s.z*wh[1][kq*4+2]+s.w*wh[1][kq*4+3];
        a2+=s.x*wh[2][kq*4]+s.y*wh[2][kq*4+1]+s.z*wh[2][kq*4+2]+s.w*wh[2][kq*4+3];
        a3+=s.x*wh[3][kq*4]+s.y*wh[3][kq*4+1]+s.z*wh[3][kq*4+2]+s.w*wh[3][kq*4+3];
      }
      RED4(a0,a1,a2,a3);
      if(l==0){ gl[wv*4+0]=a0; gl[wv*4+1]=a1; gl[wv*4+2]=a2; gl[wv*4+3]=a3; }
      if(isenc && i<T_STEPS-1){ XDOT(i+1,(i+1)&1); }   // next step's x-gates
      __syncthreads();
      if(tid<8){
        int q2=tid>>2, r2=tid&3;
        float e0,e1,e2,e3;
        if(isenc){ int par=i&1;
          e0=gl2[par][(((q2<<2)|0)<<2)+r2]; e1=gl2[par][(((q2<<2)|1)<<2)+r2];
          e2=gl2[par][(((q2<<2)|2)<<2)+r2]; e3=gl2[par][(((q2<<2)|3)<<2)+r2];
        } else { e0=xq0; e1=xq1; e2=xq2; e3=xq3; }
        float gi=bI+e0+gl[(((q2<<2)|0)<<2)+r2];
        float gf=bF+e1+gl[(((q2<<2)|1)<<2)+r2];
        float gg=bG+e2+gl[(((q2<<2)|2)<<2)+r2];
        float go=bO+e3+gl[(((q2<<2)|3)<<2)+r2];
        c_st = sigf(gf)*c_st + sigf(gi)*tanh_f(gg);
        h_st = sigf(go)*tanh_f(c_st);
        store_h(R + (size_t)(i+1)*SLOT_DW, magic, hr0+tid, h_st);
        if(isenc && i==T_STEPS-1){ F[hr0+tid]=c_st; F[2048+hr0+tid]=h_st; }
      }
    }
  } else {
    // =========== L1 role: 4 h-rows, K=2048 concat[h0|h1]; dec: fused proj ===
    const int kb = blockIdx.x-128, hr0 = kb*4;
    const int g = wv&3, rp = wv>>2;
    const int grow0 = (g<<10) + hr0 + rp*2;
    const int sb = l*36;

    float wr[2][32];                              // [W_ih | W_hh] rows, resident
    {
      const float* WI = Wih + LSTRIDE;
      const float* WH = Whh + LSTRIDE;
      const float* bp = (l<32) ? WI + (size_t)grow0*H_DIM + l*32
                               : WH + (size_t)grow0*H_DIM + (l-32)*32;
      #pragma unroll
      for(int r=0;r<2;r++){
        #pragma unroll
        for(int kq=0;kq<8;kq++){
          f4 v=*(const f4*)(bp + (size_t)r*H_DIM + kq*4);
          wr[r][kq*4+0]=v.x; wr[r][kq*4+1]=v.y; wr[r][kq*4+2]=v.z; wr[r][kq*4+3]=v.w;
        }
      }
    }
    // fused projection (dec): out row hr0+(tid>>7), k-seg (tid&127)*8
    const int pj = tid>>7, pk = (tid&127)*8;
    const int pw = 1152 + pk + ((pk>>5)<<2);
    float ow[8]; float obv=0.f;
    if(!isenc){
      f4 o0=*(const f4*)(oW + (size_t)(hr0+pj)*H_DIM + pk);
      f4 o1=*(const f4*)(oW + (size_t)(hr0+pj)*H_DIM + pk + 4);
      ow[0]=o0.x; ow[1]=o0.y; ow[2]=o0.z; ow[3]=o0.w;
      ow[4]=o1.x; ow[5]=o1.y; ow[6]=o1.z; ow[7]=o1.w;
      if(tid<4) obv = ob[hr0+tid];
    }
    float bI=0,bF=0,bG=0,bO=0,c_st=0.f,h_st=0.f;
    if(tid<4){
      int row=hr0+tid;
      const float* bi=bih+4096; const float* bh=bhh+4096;
      bI=bi[row]+bh[row];           bF=bi[row+1024]+bh[row+1024];
      bG=bi[row+2048]+bh[row+2048]; bO=bi[row+3072]+bh[row+3072];
      if(!isenc){ c_st=F[1024+row]; h_st=fh[row]; }
      store_h(R + SLOT_DW, magic, 1024+row, h_st);   // seed slot 1 (h1 half)
    }
    for(int i=1;i<=T_STEPS;++i){
      poll_fill8(R + (size_t)i*SLOT_DW + tid*8, magic,
                 &st[tid*4 + ((tid>>3)<<2)], panic);
      __syncthreads();
      float a0=0,a1=0;
      #pragma unroll
      for(int kq=0;kq<8;kq++){
        f4 s=*(const f4*)&st[sb+kq*4];
        a0+=s.x*wr[0][kq*4]+s.y*wr[0][kq*4+1]+s.z*wr[0][kq*4+2]+s.w*wr[0][kq*4+3];
        a1+=s.x*wr[1][kq*4]+s.y*wr[1][kq*4+1]+s.z*wr[1][kq*4+2]+s.w*wr[1][kq*4+3];
      }
      #pragma unroll
      for(int o=32;o;o>>=1){ a0+=__shfl_down(a0,o,64); a1+=__shfl_down(a1,o,64); }
      if(l==0){ gl[wv*2]=a0; gl[wv*2+1]=a1; }
      if(!isenc){                                  // proj partial for tp=i-2
        f4 s0=*(const f4*)&st[pw], s1=*(const f4*)&st[pw+4];
        float p = s0.x*ow[0]+s0.y*ow[1]+s0.z*ow[2]+s0.w*ow[3]
                + s1.x*ow[4]+s1.y*ow[5]+s1.z*ow[6]+s1.w*ow[7];
        #pragma unroll
        for(int o=32;o;o>>=1) p+=__shfl_down(p,o,64);
        if(l==0) gl[16+wv]=p;
      }
      __syncthreads();
      if(tid<4){
        int rp2=tid>>1, r2=tid&1;
        float gi=bI+gl[((((rp2<<2)|0))<<1)+r2];
        float gf=bF+gl[((((rp2<<2)|1))<<1)+r2];
        float gg=bG+gl[((((rp2<<2)|2))<<1)+r2];
        float go=bO+gl[((((rp2<<2)|3))<<1)+r2];
        c_st = sigf(gf)*c_st + sigf(gi)*tanh_f(gg);
        h_st = sigf(go)*tanh_f(c_st);
        store_h(R + (size_t)(i+1)*SLOT_DW, magic, 1024+hr0+tid, h_st);
        if(isenc && i==T_STEPS){ F[1024+hr0+tid]=c_st; fh_out[hr0+tid]=h_st; }
        if(!isenc && i>=2){
          float pv = gl[16+2*tid]+gl[16+2*tid+1]+obv;
          pv = pv>0.f ? pv : 0.01f*pv;
          out[(size_t)(4095-(i-2))*H_DIM + hr0+tid] = pv;
        }
      }
    }
    if(!isenc){                                    // drain tp=4095
      poll_fill4(R + (size_t)4097*SLOT_DW + 2048 + tid*4, magic,
                 &st[1152 + tid*2 + ((tid>>4)<<2)], panic);
      __syncthreads();
      f4 s0=*(const f4*)&st[pw], s1=*(const f4*)&st[pw+4];
      float p = s0.x*ow[0]+s0.y*ow[1]+s0.z*ow[2]+s0.w*ow[3]
              + s1.x*ow[4]+s1.y*ow[5]+s1.z*ow[6]+s1.w*ow[7];
      #pragma unroll
      for(int o=32;o;o>>=1) p+=__shfl_down(p,o,64);
      if(l==0) gl[16+wv]=p;
      __syncthreads();
      if(tid<4){
        float pv = gl[16+2*tid]+gl[16+2*tid+1]+obv;
        pv = pv>0.f ? pv : 0.01f*pv;
        out[hr0+tid] = pv;                         // (4095-4095)=row 0
      }
    }
  }
}

extern "C" void kernel_launch(void* const* d_in, const int* in_sizes, int n_in,
                              void* d_out, int out_size, void* d_ws, size_t ws_size,
                              hipStream_t stream) {
  const float* x    = (const float*)d_in[0];
  const float* eWih = (const float*)d_in[1];
  const float* eWhh = (const float*)d_in[2];
  const float* ebih = (const float*)d_in[3];
  const float* ebhh = (const float*)d_in[4];
  const float* dWih = (const float*)d_in[5];
  const float* dWhh = (const float*)d_in[6];
  const float* dbih = (const float*)d_in[7];
  const float* dbhh = (const float*)d_in[8];
  const float* oW   = (const float*)d_in[9];
  const float* ob   = (const float*)d_in[10];
  float* out = (float*)d_out;
  u32* ws = (u32*)d_ws;

  const size_t REGION = (size_t)NSLOT*SLOT_DW;     // dwords (~67 MB)
  u32*   R     = ws;
  float* F     = (float*)(ws + REGION);            // 3072 floats: finals
  u32*   panic = ws + REGION + 3072;
  float* fh    = out + (size_t)T_STEPS*H_DIM;      // final_hidden (output 1)

  hipMemsetAsync(d_ws, 0, (REGION + 3072 + 64)*4, stream);

  // encoder: L0+L1 lockstep, M1
  lstm_scan2<<<384,512,0,stream>>>(x, nullptr, R, M1,
      eWih, eWhh, ebih, ebhh, F, fh, nullptr, nullptr, nullptr, panic, 1);
  // decoder: L0(const input)+L1 lockstep + fused projection, M2
  lstm_scan2<<<384,512,0,stream>>>(nullptr, fh, R, M2,
      dWih, dWhh, dbih, dbhh, F, nullptr, oW, ob, out, panic, 0);
}

// Round 6
// 59320.398 us; speedup vs baseline: 2.8983x; 2.8983x over previous
//
#include <hip/hip_runtime.h>
#include <stdint.h>

// ---------------------------------------------------------------------------
// Seq2seq LSTM autoencoder (T=4096, H=1024, L=2), fp32 end-to-end.
// Round 6 = round 3 structure (known-good 3.84us/step) + spin-pressure cuts:
//   - scans 2..4 read their INPUT stream with plain cached loads (it is fully
//     materialized by the previous kernel; kernel boundary gives visibility),
//     issued before the own-h poll so they complete under the spin.
//   - adaptive backoff in the own-h poll: check, s_sleep(8), then s_sleep(2)
//     loop (round 5 showed tight spinning congests the agent-scope path).
//   - dec L0's constant input half-dot computed once, carried in a register.
// 5 sequential kernels: enc L0 -> enc L1 -> dec L0 -> dec L1 -> projection.
// Scan: 256 blocks x 256 threads (2 blocks/CU residency margin), 4 h-rows
// per block, fp32 weights in VGPRs (128/thr). h streams through LLC as fp32
// split into two self-validating tagged dwords (MAGIC<<16)|half, relaxed
// agent-scope atomics. Enc/dec reuse stream buffers with different magics.
// ---------------------------------------------------------------------------

#define T_STEPS 4096
#define H_DIM   1024
#define SLOT_DW 2048              // 1024 fp32 x 2 tagged dwords
#define NSLOT   4097
#define M1 0x7E57u
#define M2 0x7E58u
#define PANIC_ITERS (1u<<25)

using u32 = uint32_t;

static __device__ __forceinline__ float sigf(float x){ return 1.0f/(1.0f+__expf(-x)); }
static __device__ __forceinline__ float tanh_f(float x){
  x = fminf(20.f, fmaxf(-20.f, x));
  float e = __expf(-2.f*x);
  return (1.f-e)/(1.f+e);
}

static __device__ __forceinline__ float untag(u32 lo, u32 hi){
  return __uint_as_float((lo&0xFFFFu)|(hi<<16));
}
static __device__ __forceinline__ float4 untag4(const u32* q){
  float4 f;
  f.x=untag(q[0],q[1]); f.y=untag(q[2],q[3]);
  f.z=untag(q[4],q[5]); f.w=untag(q[6],q[7]);
  return f;
}

// Poll this thread's 8 dwords of a slot until tagged; deposit 4 fp32 into LDS.
// Backoff: immediate check -> sleep(8) -> sleep(2) loop.
static __device__ __forceinline__ void poll_fill(const u32* slot, u32 magic,
                                                 float* st, int wb, int tid,
                                                 u32* panic){
  const u32* q = slot + tid*8;
  u32 v[8]; u32 it=0;
  for(;;){
    #pragma unroll
    for(int m=0;m<8;m++) v[m]=__hip_atomic_load(q+m,__ATOMIC_RELAXED,__HIP_MEMORY_SCOPE_AGENT);
    bool ok = true;
    #pragma unroll
    for(int m=0;m<8;m++) ok = ok && ((v[m]>>16)==magic);
    if(ok) break;
    ++it;
    if(it==1){ __builtin_amdgcn_s_sleep(8); continue; }
    if((it & 255u)==0u){
      if(__hip_atomic_load(panic,__ATOMIC_RELAXED,__HIP_MEMORY_SCOPE_AGENT)==0xDEADBEEFu) break;
      if(it>PANIC_ITERS){ __hip_atomic_store(panic,0xDEADBEEFu,__ATOMIC_RELAXED,__HIP_MEMORY_SCOPE_AGENT); break; }
    }
    __builtin_amdgcn_s_sleep(2);
  }
  float4 f;
  f.x=untag(v[0],v[1]); f.y=untag(v[2],v[3]);
  f.z=untag(v[4],v[5]); f.w=untag(v[6],v[7]);
  *(float4*)(st+wb)=f;
}

static __device__ __forceinline__ void store_h(u32* slot, u32 magic, int e, float h){
  u32 b=__float_as_uint(h);
  __hip_atomic_store(slot+2*e,   (magic<<16)|(b&0xFFFFu), __ATOMIC_RELAXED,__HIP_MEMORY_SCOPE_AGENT);
  __hip_atomic_store(slot+2*e+1, (magic<<16)|(b>>16),     __ATOMIC_RELAXED,__HIP_MEMORY_SCOPE_AGENT);
}

// One LSTM layer over T steps.
// mode 0: input = raw x (plain loads).  mode 1/3: input = tagged stream,
// fully materialized by the previous kernel -> PLAIN cached loads (no spin),
// issued before the own-h poll.  mode 2: input constant (staged once; its
// half-dot is hoisted out of the loop).
// Block kb owns h-rows hr0..hr0+3. Wave w = gate (i,f,g,o); lane l = one
// 32-col segment of the concatenated K=2048 [W_ih | W_hh] dot (lanes 0..31 =
// input half, lanes 32..63 = h half).
__global__ __launch_bounds__(256,2) void lstm_scan(
    const float* __restrict__ xin,
    const u32*  __restrict__ instream,
    u32*        __restrict__ own,
    u32 m_own,
    const float* __restrict__ Wih, const float* __restrict__ Whh,
    const float* __restrict__ bih, const float* __restrict__ bhh,
    const float* __restrict__ c0,      // null -> zeros
    float*       __restrict__ cout,    // final c per row
    const u32*  __restrict__ h0slot,   // tagged slot holding h0; null -> zeros
    float*       __restrict__ fh_out,  // if non-null: write final h (enc L1)
    u32* __restrict__ panic,
    int mode)
{
  // padded stage: element E at word E + 4*(E>>5); IN part 0..1151, H 1152..2303
  __shared__ __align__(16) float st[2304];
  __shared__ float gl[16];

  const int kb=blockIdx.x, tid=threadIdx.x;
  const int hr0=kb*4;
  const int w=tid>>6, l=tid&63;
  const int grow0=(w<<10)+hr0;             // first of 4 owned gate rows
  const int fb  = tid*4 + ((tid>>3)<<2);   // stage word base, IN part
  const int fbH = 1152+fb;                 // stage word base, H part
  const int sb  = l*36;                    // dot segment word base

  // fp32 weights in VGPRs: 4 rows x 32-col segment
  float wr0[32],wr1[32],wr2[32],wr3[32];
  {
    const float* srcb = (l<32) ? Wih + (size_t)grow0*H_DIM + l*32
                               : Whh + (size_t)grow0*H_DIM + (l-32)*32;
    #pragma unroll
    for(int i=0;i<8;i++){
      float4 a0=*(const float4*)(srcb + i*4);
      float4 a1=*(const float4*)(srcb + 1024 + i*4);
      float4 a2=*(const float4*)(srcb + 2048 + i*4);
      float4 a3=*(const float4*)(srcb + 3072 + i*4);
      wr0[4*i]=a0.x; wr0[4*i+1]=a0.y; wr0[4*i+2]=a0.z; wr0[4*i+3]=a0.w;
      wr1[4*i]=a1.x; wr1[4*i+1]=a1.y; wr1[4*i+2]=a1.z; wr1[4*i+3]=a1.w;
      wr2[4*i]=a2.x; wr2[4*i+1]=a2.y; wr2[4*i+2]=a2.z; wr2[4*i+3]=a2.w;
      wr3[4*i]=a3.x; wr3[4*i+1]=a3.y; wr3[4*i+2]=a3.z; wr3[4*i+3]=a3.w;
    }
  }

  float bI=0,bF=0,bG=0,bO=0,c_st=0.f,h_st=0.f;   // valid for tid<4
  if(tid<4){
    int o=hr0+tid;
    bI=bih[o]       + bhh[o];
    bF=bih[o+1024]  + bhh[o+1024];
    bG=bih[o+2048]  + bhh[o+2048];
    bO=bih[o+3072]  + bhh[o+3072];
    if(c0)     c_st=c0[o];
    if(h0slot) h_st=untag(h0slot[2*o], h0slot[2*o+1]);
    store_h(own, m_own, o, h_st);              // own slot 0
  }

  // mode 2: constant input staged once; its half-dot hoisted out of the loop
  float pin0=0.f,pin1=0.f,pin2=0.f,pin3=0.f;
  if(mode==2){
    float4 f = untag4(instream + tid*8);
    *(float4*)(st+fb)=f;
    __syncthreads();
    if(l<32){
      #pragma unroll
      for(int i=0;i<8;i++){
        float4 s=*(const float4*)(st+sb+i*4);
        pin0+=s.x*wr0[4*i]+s.y*wr0[4*i+1]+s.z*wr0[4*i+2]+s.w*wr0[4*i+3];
        pin1+=s.x*wr1[4*i]+s.y*wr1[4*i+1]+s.z*wr1[4*i+2]+s.w*wr1[4*i+3];
        pin2+=s.x*wr2[4*i]+s.y*wr2[4*i+1]+s.z*wr2[4*i+2]+s.w*wr2[4*i+3];
        pin3+=s.x*wr3[4*i]+s.y*wr3[4*i+1]+s.z*wr3[4*i+2]+s.w*wr3[4*i+3];
      }
    }
    __syncthreads();
  }

  for(int t=0;t<T_STEPS;++t){
    if(mode==0){
      float4 xv=*(const float4*)(xin + (size_t)t*H_DIM + tid*4);
      *(float4*)(st+fb)=xv;
    } else if(mode!=2){
      // input stream fully materialized: plain cached loads, no spin.
      // Issued before the own-h poll so they complete under the spin.
      const u32* q = instream + (size_t)(t+1)*SLOT_DW + tid*8;
      uint4 ia=*(const uint4*)(q);
      uint4 ib=*(const uint4*)(q+4);
      float4 fi;
      fi.x=untag(ia.x,ia.y); fi.y=untag(ia.z,ia.w);
      fi.z=untag(ib.x,ib.y); fi.w=untag(ib.z,ib.w);
      *(float4*)(st+fb)=fi;
    }
    poll_fill(own + (size_t)t*SLOT_DW, m_own, st, fbH, tid, panic);
    __syncthreads();
    float p0,p1,p2,p3;
    if(mode==2){
      p0=pin0; p1=pin1; p2=pin2; p3=pin3;    // lanes<32 carry the constant half
      if(l>=32){
        #pragma unroll
        for(int i=0;i<8;i++){
          float4 s=*(const float4*)(st+sb+i*4);
          p0+=s.x*wr0[4*i]+s.y*wr0[4*i+1]+s.z*wr0[4*i+2]+s.w*wr0[4*i+3];
          p1+=s.x*wr1[4*i]+s.y*wr1[4*i+1]+s.z*wr1[4*i+2]+s.w*wr1[4*i+3];
          p2+=s.x*wr2[4*i]+s.y*wr2[4*i+1]+s.z*wr2[4*i+2]+s.w*wr2[4*i+3];
          p3+=s.x*wr3[4*i]+s.y*wr3[4*i+1]+s.z*wr3[4*i+2]+s.w*wr3[4*i+3];
        }
      }
    } else {
      p0=0.f;p1=0.f;p2=0.f;p3=0.f;
      #pragma unroll
      for(int i=0;i<8;i++){
        float4 s=*(const float4*)(st+sb+i*4);
        p0+=s.x*wr0[4*i]+s.y*wr0[4*i+1]+s.z*wr0[4*i+2]+s.w*wr0[4*i+3];
        p1+=s.x*wr1[4*i]+s.y*wr1[4*i+1]+s.z*wr1[4*i+2]+s.w*wr1[4*i+3];
        p2+=s.x*wr2[4*i]+s.y*wr2[4*i+1]+s.z*wr2[4*i+2]+s.w*wr2[4*i+3];
        p3+=s.x*wr3[4*i]+s.y*wr3[4*i+1]+s.z*wr3[4*i+2]+s.w*wr3[4*i+3];
      }
    }
    #pragma unroll
    for(int off=32;off;off>>=1){
      p0+=__shfl_down(p0,off,64); p1+=__shfl_down(p1,off,64);
      p2+=__shfl_down(p2,off,64); p3+=__shfl_down(p3,off,64);
    }
    if(l==0){ gl[w*4+0]=p0; gl[w*4+1]=p1; gl[w*4+2]=p2; gl[w*4+3]=p3; }
    __syncthreads();
    if(tid<4){
      float gi=bI+gl[tid], gf=bF+gl[4+tid], gg=bG+gl[8+tid], go=bO+gl[12+tid];
      c_st = sigf(gf)*c_st + sigf(gi)*tanh_f(gg);
      h_st = sigf(go)*tanh_f(c_st);
      store_h(own + (size_t)(t+1)*SLOT_DW, m_own, hr0+tid, h_st);
      if(t==T_STEPS-1){
        cout[hr0+tid]=c_st;
        if(fh_out) fh_out[hr0+tid]=h_st;
      }
    }
    __syncthreads();
  }
}

// out[(4095-tp), o] = leaky( sum_k oW[o,k] * h1d[tp][k] + ob[o] )
__global__ __launch_bounds__(256) void proj_out(
    const u32* __restrict__ SB, const float* __restrict__ oW,
    const float* __restrict__ ob, float* __restrict__ out)
{
  __shared__ __align__(16) float hb[1024];
  const int tp=blockIdx.x, tid=threadIdx.x;
  float4 f = untag4(SB + (size_t)(tp+1)*SLOT_DW + tid*8);
  *(float4*)(hb + tid*4)=f;
  __syncthreads();
  #pragma unroll
  for(int j=0;j<4;j++){
    int o = tid + 256*j;
    const float* wr = oW + (size_t)o*H_DIM;
    float acc=0.f;
    for(int k=0;k<1024;k+=4){
      float4 wv=*(const float4*)(wr+k);
      acc += wv.x*hb[k]+wv.y*hb[k+1]+wv.z*hb[k+2]+wv.w*hb[k+3];
    }
    acc += ob[o];
    acc = acc>0.f ? acc : 0.01f*acc;
    out[(size_t)(4095-tp)*H_DIM + o]=acc;
  }
}

extern "C" void kernel_launch(void* const* d_in, const int* in_sizes, int n_in,
                              void* d_out, int out_size, void* d_ws, size_t ws_size,
                              hipStream_t stream) {
  const float* x    = (const float*)d_in[0];
  const float* eWih = (const float*)d_in[1];
  const float* eWhh = (const float*)d_in[2];
  const float* ebih = (const float*)d_in[3];
  const float* ebhh = (const float*)d_in[4];
  const float* dWih = (const float*)d_in[5];
  const float* dWhh = (const float*)d_in[6];
  const float* dbih = (const float*)d_in[7];
  const float* dbhh = (const float*)d_in[8];
  const float* oW   = (const float*)d_in[9];
  const float* ob   = (const float*)d_in[10];
  float* out = (float*)d_out;
  u32* ws = (u32*)d_ws;

  const size_t REGION = (size_t)NSLOT*SLOT_DW;
  u32*   SA    = ws;
  u32*   SB    = ws + REGION;
  float* CA    = (float*)(ws + 2*REGION);      // 2048 floats: enc c finals
  u32*   panic = ws + 2*REGION + 2048;
  const size_t LSTRIDE = (size_t)4096*1024;    // per-layer weight stride

  // clear tags + c buffer + panic (0xAA poison must never look like MAGIC)
  size_t clr_bytes = (2*REGION + 2048 + 64)*4;
  hipMemsetAsync(d_ws, 0, clr_bytes, stream);

  // encoder L0: input x, stream SA (M1), zero init
  lstm_scan<<<256,256,0,stream>>>(x, SA, SA, M1,
      eWih, eWhh, ebih, ebhh,
      nullptr, CA, nullptr, nullptr, panic, 0);
  // encoder L1: input SA (plain reads), stream SB (M1); writes final_hidden
  lstm_scan<<<256,256,0,stream>>>(nullptr, SA, SB, M1,
      eWih+LSTRIDE, eWhh+LSTRIDE, ebih+4096, ebhh+4096,
      nullptr, CA+1024, nullptr, out + (size_t)T_STEPS*H_DIM, panic, 1);
  // decoder L0: const input = final_hidden (SB slot 4096, M1 payload),
  // stream SA reused (M2), init = enc L0 final state
  lstm_scan<<<256,256,0,stream>>>(nullptr, SB + (size_t)4096*SLOT_DW, SA, M2,
      dWih, dWhh, dbih, dbhh,
      CA, CA, SA + (size_t)4096*SLOT_DW, nullptr, panic, 2);
  // decoder L1: input SA (plain reads), stream SB reused (M2),
  // init = enc L1 final state
  lstm_scan<<<256,256,0,stream>>>(nullptr, SA, SB, M2,
      dWih+LSTRIDE, dWhh+LSTRIDE, dbih+4096, dbhh+4096,
      CA+1024, CA+1024, SB + (size_t)4096*SLOT_DW, nullptr, panic, 3);
  // projection + leaky ReLU + flip
  proj_out<<<4096,256,0,stream>>>(SB, oW, ob, out);
}